// Round 6
// baseline (389.436 us; speedup 1.0000x reference)
//
#include <hip/hip_runtime.h>

#define NVOC 32000
#define NV4  (NVOC / 4)
#define MASKID 31999
#define NBINS 1024
#define NTHR 1024
#define LISTCAP 2048
#define KITER 8

typedef unsigned int u32;
typedef unsigned long long u64;

// log2-spaced bins directly from the f32 bit pattern of e in (0,1]:
// 64 bins per octave; below 2^-18 -> bin 0; top -> 1023. Monotone in e.
__device__ __forceinline__ int bin_e(float e) {
    int v = (int)(__float_as_uint(e) >> 17) - 6976;   // 6976 = (127-18)<<6
    v = v < 0 ? 0 : v;
    return v > (NBINS - 1) ? (NBINS - 1) : v;
}

// e in [0,1] -> fixed-point mass at 2^-32 (f32 arithmetic, monotone in e)
__device__ __forceinline__ u32 fix32(float e) {
    float x = e * 4294967296.0f;
    x = fminf(x, 4294967040.0f);
    return (u32)x;
}

__global__ __launch_bounds__(NTHR, 8) void mdlm_kernel(
    const int* __restrict__ xin,
    const float* __restrict__ logits,
    const float* __restrict__ tin,
    const float* __restrict__ uin,
    float* __restrict__ out,
    int rows)
{
    __shared__ u64 sHist[NBINS];        // 8 KB
    __shared__ u32 sList[LISTCAP];      // 8 KB
    __shared__ double sRedD[16];
    __shared__ float sRedF[16];
    __shared__ int sRedI[16];
    __shared__ float sZmax, sTT;
    __shared__ int sCnt, sB, sCross, sMaxDrop;
    __shared__ u32 sTau;
    __shared__ u64 sAs, sSfp;

    const int row = blockIdx.x;
    if (row >= rows) return;
    const int tid = threadIdx.x;
    const float4* lrow4 = (const float4*)(logits + (size_t)row * NVOC);
    const float4* urow4 = (const float4*)(uin + (size_t)row * NVOC);
    float* prow = out + (size_t)rows + (size_t)row * NVOC;

    sHist[tid] = 0ULL;  // NBINS == NTHR
    if (tid == 0) {
        sCnt = 0; sB = -1; sCross = 0; sMaxDrop = -1; sTau = 0xFFFFFFFFu;
        sAs = 0ULL; sSfp = 0ULL;
        sTT = tin[0];
    }
    __syncthreads();

    // ---- pass A: load z into registers (the ONLY logits read), row max ----
    float4 ez[KITER];
    float lmax = -3.0e38f;
#pragma unroll
    for (int k = 0; k < KITER; ++k) {
        const int v4 = tid + k * NTHR;
        if (v4 < NV4) {
            float4 f = lrow4[v4];
            if (v4 == (MASKID >> 2)) f.w = -1000000.0f;   // MASKID % 4 == 3
            ez[k] = f;
            lmax = fmaxf(lmax, fmaxf(fmaxf(f.x, f.y), fmaxf(f.z, f.w)));
        } else {
            ez[k] = make_float4(-1.0e38f, -1.0e38f, -1.0e38f, -1.0e38f);
        }
    }
    for (int off = 32; off > 0; off >>= 1)
        lmax = fmaxf(lmax, __shfl_down(lmax, off, 64));
    if ((tid & 63) == 0) sRedF[tid >> 6] = lmax;
    __syncthreads();
    if (tid == 0) {
        float m = sRedF[0];
        for (int w = 1; w < NTHR / 64; ++w) m = fmaxf(m, sRedF[w]);
        sZmax = m;
    }
    __syncthreads();
    const float zmax = sZmax;

    // ---- pass B: e = exp(z - zmax) in-place in registers; mass histogram ----
#pragma unroll
    for (int k = 0; k < KITER; ++k) {
        const int v4 = tid + k * NTHR;
        float4 f = ez[k];
        f.x = __expf(f.x - zmax);
        f.y = __expf(f.y - zmax);
        f.z = __expf(f.z - zmax);
        f.w = __expf(f.w - zmax);
        ez[k] = f;
        if (v4 < NV4) {
            atomicAdd(&sHist[bin_e(f.x)], (u64)fix32(f.x));
            atomicAdd(&sHist[bin_e(f.y)], (u64)fix32(f.y));
            atomicAdd(&sHist[bin_e(f.z)], (u64)fix32(f.z));
            atomicAdd(&sHist[bin_e(f.w)], (u64)fix32(f.w));
        }
    }
    __syncthreads();

    // ---- pass C: inclusive suffix scan over bins; Z = sHist[0] afterwards ----
    for (int dlt = 1; dlt < NBINS; dlt <<= 1) {
        u64 vv = (tid + dlt < NBINS) ? sHist[tid + dlt] : 0ULL;
        __syncthreads();
        sHist[tid] += vv;
        __syncthreads();
    }
    const double T = 0.9 * (double)sHist[0];   // total mass Z = suffix sum at bin 0
    // crossing detection: A_strict(k) < T < A_incl(k)
    {
        u64 Ai = sHist[tid];
        u64 As = (tid + 1 < NBINS) ? sHist[tid + 1] : 0ULL;
        bool dropped = ((double)As >= T);
        bool keptf = ((double)Ai <= T);
        if (dropped) atomicMax(&sMaxDrop, tid);
        if (!dropped && !keptf) { sB = tid; sCross = 1; }
    }
    __syncthreads();
    if (tid == 0) {
        int B = sCross ? sB : sMaxDrop;
        sB = B;
        u64 As;
        if (B < 0) As = sHist[0];                       // nothing dropped: keep all
        else As = (B + 1 < NBINS) ? sHist[B + 1] : 0ULL;
        sAs = As;
        if (!sCross) sSfp = As;                         // kept mass = strict-above B
    }
    __syncthreads();

    const int Bst = sB;
    const int cross = sCross;

    // ---- pass D/E: exact resolution inside the crossing bin (register scan) ----
    if (cross) {
#pragma unroll
        for (int k = 0; k < KITER; ++k) {
            const int v4 = tid + k * NTHR;
            if (v4 < NV4) {
                float4 f = ez[k];
                float ee[4] = {f.x, f.y, f.z, f.w};
#pragma unroll
                for (int e4 = 0; e4 < 4; ++e4) {
                    if (bin_e(ee[e4]) == Bst) {
                        int pos = atomicAdd(&sCnt, 1);
                        if (pos < LISTCAP) sList[pos] = fix32(ee[e4]);
                    }
                }
            }
        }
        __syncthreads();
        const int K = sCnt < LISTCAP ? sCnt : LISTCAP;
        for (int jj = tid; jj < K; jj += NTHR) {
            u32 mj = sList[jj];
            u64 s = sAs;
            for (int q2 = 0; q2 < K; ++q2) {
                u32 mv = sList[q2];
                if (mv >= mj) s += (u64)mv;
            }
            if ((double)s <= T) atomicMin(&sTau, mj);   // kept
        }
        __syncthreads();
        if (tid == 0) sSfp = sAs;
        __syncthreads();
        u32 tl = sTau;
        if (tl != 0xFFFFFFFFu) {
            u64 part = 0ULL;
            for (int q2 = tid; q2 < K; q2 += NTHR) {
                u32 mv = sList[q2];
                if (mv >= tl) part += (u64)mv;
            }
            if (part) atomicAdd(&sSfp, part);
        }
        __syncthreads();
    }

    // unified kept threshold: kept <=> fix32(e) >= tauU
    u32 tauU;
    {
        u32 tv = sTau;
        u32 edgefix = 0u;
        if (Bst >= 0) edgefix = fix32(__uint_as_float((u32)(Bst + 1 + 6976) << 17));
        if (cross) tauU = (tv != 0xFFFFFFFFu) ? tv : edgefix;
        else       tauU = (Bst < 0) ? 0u : edgefix;
    }

    const double invSd = 4294967296.0 / (double)sSfp;
    const float invSf = (float)invSd;

    // mask_prob in f64, replicating the reference expression order
    const double td = (double)sTT;
    const double mpd = ((1.0 - 1e-3) * (td - 0.05)) / ((1.0 - 1e-3) * td);
    const double omd = 1.0 - mpd;
    const float mpf = (float)mpd;
    const float omf = (float)omd;

    // ---- pass F: write p_x0, f32-screen gumbel-ratio, top-2/thread ----
    float r1 = -3.0e38f, r2 = -3.0e38f;
    int   i1 = 0,        i2 = 0;
    float e1 = 0.0f,     e2 = 0.0f;
    float u1 = 0.0f,     u2 = 0.0f;
#pragma unroll
    for (int k = 0; k < KITER; ++k) {
        const int v4 = tid + k * NTHR;
        if (v4 < NV4) {
            float4 uf = urow4[v4];
            float4 f = ez[k];
            float uu[4] = {uf.x, uf.y, uf.z, uf.w};
            float ee[4] = {f.x, f.y, f.z, f.w};
            float pp[4];
            const int i0 = v4 * 4;
#pragma unroll
            for (int e4 = 0; e4 < 4; ++e4) {
                const int i = i0 + e4;
                float e = ee[e4];
                bool kept = (fix32(e) >= tauU);
                float p = kept ? e * invSf : 0.0f;
                pp[e4] = p;
                float q = p * omf;                 // MASKID handled after the loop
                float ug = uu[e4] + 1e-10f;
                float l1 = __logf(ug);
                float w = 1e-10f - l1;             // -log(u+1e-10) + 1e-10
                float g = -__logf(w);
                float r = q * __builtin_amdgcn_rcpf(g + 1e-10f);
                if (r > r1) {
                    r2 = r1; i2 = i1; e2 = e1; u2 = u1;
                    r1 = r;  i1 = i;  e1 = e;  u1 = uu[e4];
                } else if (r > r2) {
                    r2 = r;  i2 = i;  e2 = e;  u2 = uu[e4];
                }
            }
            float4 po;
            po.x = pp[0]; po.y = pp[1]; po.z = pp[2]; po.w = pp[3];
            ((float4*)prow)[v4] = po;
        }
    }
    // inject the MASK candidate (q = mask_prob), owned by the thread that processed it
    if (tid == ((MASKID >> 2) & (NTHR - 1))) {
        float um = ((const float*)urow4)[MASKID];
        float ug = um + 1e-10f;
        float l1 = __logf(ug);
        float w = 1e-10f - l1;
        float g = -__logf(w);
        float rm = mpf * __builtin_amdgcn_rcpf(g + 1e-10f);
        if (rm > r1) {
            r2 = r1; i2 = i1; e2 = e1; u2 = u1;
            r1 = rm; i1 = MASKID; e1 = 0.0f; u1 = um;
        } else if (rm > r2) {
            r2 = rm; i2 = MASKID; e2 = 0.0f; u2 = um;
        }
    }

    // ---- refine the 2 candidates: g in f64 (the precision-critical part) ----
    double best; int bidx;
    {
        double q;
        if (i1 == MASKID) q = mpd;
        else {
            bool k = (fix32(e1) >= tauU);
            q = k ? (double)e1 * invSd * omd : 0.0;
        }
        double g = -log(-log((double)u1 + 1e-10) + 1e-10);
        best = q / (g + 1e-10);
        bidx = i1;
    }
    {
        double q;
        if (i2 == MASKID) q = mpd;
        else {
            bool k = (fix32(e2) >= tauU);
            q = k ? (double)e2 * invSd * omd : 0.0;
        }
        double g = -log(-log((double)u2 + 1e-10) + 1e-10);
        double rd = q / (g + 1e-10);
        if (rd > best || (rd == best && i2 < bidx)) { best = rd; bidx = i2; }
    }

    const int NW = NTHR / 64;
    __shared__ double sBestD[NTHR / 64];
    for (int off = 32; off > 0; off >>= 1) {
        double ov = __shfl_down(best, off, 64);
        int oi = __shfl_down(bidx, off, 64);
        if (ov > best || (ov == best && oi < bidx)) { best = ov; bidx = oi; }
    }
    if ((tid & 63) == 0) { sBestD[tid >> 6] = best; sRedI[tid >> 6] = bidx; }
    __syncthreads();
    if (tid == 0) {
        best = sBestD[0]; bidx = sRedI[0];
        for (int w = 1; w < NW; ++w) {
            double ov = sBestD[w]; int oi = sRedI[w];
            if (ov > best || (ov == best && oi < bidx)) { best = ov; bidx = oi; }
        }
        int xv = xin[row];
        out[row] = (float)((xv == MASKID) ? bidx : xv);
    }
}

extern "C" void kernel_launch(void* const* d_in, const int* in_sizes, int n_in,
                              void* d_out, int out_size, void* d_ws, size_t ws_size,
                              hipStream_t stream) {
    const int* x = (const int*)d_in[0];
    const float* logits = (const float*)d_in[1];
    const float* t = (const float*)d_in[2];
    const float* u = (const float*)d_in[3];
    float* out = (float*)d_out;
    const int rows = in_sizes[0];  // B*S = 2048
    hipLaunchKernelGGL(mdlm_kernel, dim3(rows), dim3(NTHR), 0, stream,
                       x, logits, t, u, out, rows);
}

// Round 7
// 376.798 us; speedup vs baseline: 1.0335x; 1.0335x over previous
//
#include <hip/hip_runtime.h>

#define NVOC 32000
#define NV4  (NVOC / 4)   // 8000
#define MASKID 31999
#define NBINS 1024
#define NTHR 1024
#define LISTCAP 2048

typedef unsigned int u32;
typedef unsigned long long u64;

// log2-spaced bins from the f32 bit pattern of e in (0,1]: 64 bins/octave.
__device__ __forceinline__ int bin_e(float e) {
    int v = (int)(__float_as_uint(e) >> 17) - 6976;   // 6976 = (127-18)<<6
    v = v < 0 ? 0 : v;
    return v > (NBINS - 1) ? (NBINS - 1) : v;
}

// e in [0,1] -> fixed-point mass at 2^-32 (f32 arithmetic, monotone in e)
__device__ __forceinline__ u32 fix32(float e) {
    float x = e * 4294967296.0f;
    x = fminf(x, 4294967040.0f);
    return (u32)x;
}

__global__ __launch_bounds__(NTHR, 8) void mdlm_kernel(
    const int* __restrict__ xin,
    const float* __restrict__ logits,
    const float* __restrict__ tin,
    const float* __restrict__ uin,
    float* __restrict__ out,
    int rows)
{
    __shared__ u64 sHist[NBINS];        // 8 KB
    __shared__ u32 sList[LISTCAP];      // 8 KB
    __shared__ float sRedF[16];
    __shared__ int sRedI[16];
    __shared__ double sRedD[16];
    __shared__ float sZmax, sTT;
    __shared__ int sCnt, sB, sCross, sMaxDrop;
    __shared__ u32 sTau;
    __shared__ u64 sAs, sSfp;

    const int row = blockIdx.x;
    if (row >= rows) return;
    const int tid = threadIdx.x;
    const float4* lrow4 = (const float4*)(logits + (size_t)row * NVOC);
    const float4* urow4 = (const float4*)(uin + (size_t)row * NVOC);
    float* prow = out + (size_t)rows + (size_t)row * NVOC;

    sHist[tid] = 0ULL;  // NBINS == NTHR
    if (tid == 0) {
        sCnt = 0; sB = -1; sCross = 0; sMaxDrop = -1; sTau = 0xFFFFFFFFu;
        sAs = 0ULL; sSfp = 0ULL;
        sTT = tin[0];
    }
    __syncthreads();

    // ---- pass A: load z into named regs (the ONLY logits read), row max ----
    float4 ez0, ez1, ez2, ez3, ez4, ez5, ez6, ez7;
    float lmax = -3.0e38f;
#define LOADK(K) { float4 f = lrow4[tid + (K)*NTHR]; ez##K = f; \
    lmax = fmaxf(lmax, fmaxf(fmaxf(f.x, f.y), fmaxf(f.z, f.w))); }
    LOADK(0) LOADK(1) LOADK(2) LOADK(3) LOADK(4) LOADK(5) LOADK(6)
    if (tid < 832) {                    // wave-uniform: tids 0..831 = waves 0..12
        float4 f = lrow4[tid + 7 * NTHR];
        if (tid == 831) f.w = -1000000.0f;   // element 31999 = MASKID
        ez7 = f;
        lmax = fmaxf(lmax, fmaxf(fmaxf(f.x, f.y), fmaxf(f.z, f.w)));
    }
#undef LOADK
    for (int off = 32; off > 0; off >>= 1)
        lmax = fmaxf(lmax, __shfl_down(lmax, off, 64));
    if ((tid & 63) == 0) sRedF[tid >> 6] = lmax;
    __syncthreads();
    if (tid == 0) {
        float m = sRedF[0];
        for (int w = 1; w < 16; ++w) m = fmaxf(m, sRedF[w]);
        sZmax = m;
    }
    __syncthreads();
    const float zmax = sZmax;

    // ---- pass B: e = exp(z - zmax) in-place; u64 mass histogram ----
#define EXPK(K) { float4 f = ez##K; \
    f.x = __expf(f.x - zmax); f.y = __expf(f.y - zmax); \
    f.z = __expf(f.z - zmax); f.w = __expf(f.w - zmax); \
    ez##K = f; \
    atomicAdd(&sHist[bin_e(f.x)], (u64)fix32(f.x)); \
    atomicAdd(&sHist[bin_e(f.y)], (u64)fix32(f.y)); \
    atomicAdd(&sHist[bin_e(f.z)], (u64)fix32(f.z)); \
    atomicAdd(&sHist[bin_e(f.w)], (u64)fix32(f.w)); }
    EXPK(0) EXPK(1) EXPK(2) EXPK(3) EXPK(4) EXPK(5) EXPK(6)
    if (tid < 832) { EXPK(7) }
    else { ez7 = make_float4(0.0f, 0.0f, 0.0f, 0.0f); }
#undef EXPK
    __syncthreads();

    // ---- pass C: inclusive suffix scan over bins; Z = sHist[0] afterwards ----
    for (int dlt = 1; dlt < NBINS; dlt <<= 1) {
        u64 vv = (tid + dlt < NBINS) ? sHist[tid + dlt] : 0ULL;
        __syncthreads();
        sHist[tid] += vv;
        __syncthreads();
    }
    const double T = 0.9 * (double)sHist[0];
    // crossing detection: A_strict(k) < T < A_incl(k)
    {
        u64 Ai = sHist[tid];
        u64 As = (tid + 1 < NBINS) ? sHist[tid + 1] : 0ULL;
        bool dropped = ((double)As >= T);
        bool keptf = ((double)Ai <= T);
        if (dropped) atomicMax(&sMaxDrop, tid);
        if (!dropped && !keptf) { sB = tid; sCross = 1; }
    }
    __syncthreads();
    if (tid == 0) {
        int B = sCross ? sB : sMaxDrop;
        sB = B;
        u64 As;
        if (B < 0) As = sHist[0];                       // nothing dropped: keep all
        else As = (B + 1 < NBINS) ? sHist[B + 1] : 0ULL;
        sAs = As;
        if (!sCross) sSfp = As;                         // kept mass = strict-above B
    }
    __syncthreads();

    const int Bst = sB;
    const int cross = sCross;

    // ---- pass D/E: exact resolution inside the crossing bin (register scan) ----
    if (cross) {
#define LISTC(E) { u32 m = fix32(E); \
    if (m && bin_e(E) == Bst) { int pos = atomicAdd(&sCnt, 1); if (pos < LISTCAP) sList[pos] = m; } }
#define LISTK(K) { float4 f = ez##K; LISTC(f.x) LISTC(f.y) LISTC(f.z) LISTC(f.w) }
        LISTK(0) LISTK(1) LISTK(2) LISTK(3) LISTK(4) LISTK(5) LISTK(6)
        if (tid < 832) { LISTK(7) }
#undef LISTK
#undef LISTC
        __syncthreads();
        const int K = sCnt < LISTCAP ? sCnt : LISTCAP;
        for (int jj = tid; jj < K; jj += NTHR) {
            u32 mj = sList[jj];
            u64 s = sAs;
            for (int q2 = 0; q2 < K; ++q2) {
                u32 mv = sList[q2];
                if (mv >= mj) s += (u64)mv;
            }
            if ((double)s <= T) atomicMin(&sTau, mj);   // kept
        }
        __syncthreads();
        if (tid == 0) sSfp = sAs;
        __syncthreads();
        u32 tl = sTau;
        if (tl != 0xFFFFFFFFu) {
            u64 part = 0ULL;
            for (int q2 = tid; q2 < K; q2 += NTHR) {
                u32 mv = sList[q2];
                if (mv >= tl) part += (u64)mv;
            }
            if (part) atomicAdd(&sSfp, part);
        }
        __syncthreads();
    }

    // unified kept threshold: kept <=> fix32(e) >= tauU
    u32 tauU;
    {
        u32 tv = sTau;
        u32 edgefix = 0u;
        if (Bst >= 0) edgefix = fix32(__uint_as_float((u32)(Bst + 1 + 6976) << 17));
        if (cross) tauU = (tv != 0xFFFFFFFFu) ? tv : edgefix;
        else       tauU = (Bst < 0) ? 0u : edgefix;
    }

    const float invSf = (float)(4294967296.0 / (double)sSfp);
    float mpf, omf;
    {
        double td = (double)sTT;
        double mpd = ((1.0 - 1e-3) * (td - 0.05)) / ((1.0 - 1e-3) * td);
        mpf = (float)mpd;
        omf = (float)(1.0 - mpd);
    }

    // ---- pass F: write p_x0, f32-screen gumbel-ratio, top-2 (r,q,i)/thread ----
    float r1 = -3.0e38f, r2 = -3.0e38f;
    float q1 = 0.0f,     q2 = 0.0f;
    int   i1 = 0,        i2 = 0;
#define SCREEN(E, U, IDX, PO) { \
    float p = (fix32(E) >= tauU) ? (E) * invSf : 0.0f; \
    PO = p; \
    float q = p * omf; \
    float g = -__logf(1e-10f - __logf((U) + 1e-10f)); \
    float r = q * __builtin_amdgcn_rcpf(g + 1e-10f); \
    if (r > r1)      { r2 = r1; q2 = q1; i2 = i1; r1 = r; q1 = q; i1 = (IDX); } \
    else if (r > r2) { r2 = r;  q2 = q;  i2 = (IDX); } }
#define FK(K) { \
    const int v4 = tid + (K)*NTHR; \
    float4 uf = urow4[v4]; \
    float4 f = ez##K; \
    float4 po; \
    const int i0 = v4 * 4; \
    SCREEN(f.x, uf.x, i0 + 0, po.x) \
    SCREEN(f.y, uf.y, i0 + 1, po.y) \
    SCREEN(f.z, uf.z, i0 + 2, po.z) \
    SCREEN(f.w, uf.w, i0 + 3, po.w) \
    ((float4*)prow)[v4] = po; }
    FK(0) FK(1) FK(2) FK(3) FK(4) FK(5) FK(6)
    if (tid < 832) { FK(7) }
#undef FK
#undef SCREEN
    // inject the MASK candidate (q = mask_prob)
    if (tid == 831) {
        float um = ((const float*)urow4)[MASKID];
        float g = -__logf(1e-10f - __logf(um + 1e-10f));
        float rm = mpf * __builtin_amdgcn_rcpf(g + 1e-10f);
        if (rm > r1)      { r2 = r1; q2 = q1; i2 = i1; r1 = rm; q1 = mpf; i1 = MASKID; }
        else if (rm > r2) { r2 = rm; q2 = mpf; i2 = MASKID; }
    }

    // ---- refine the 2 candidates: g in f64 (the precision-critical part) ----
    double best; int bidx;
    {
        const float* urowf = (const float*)urow4;
        double g1 = -log(-log((double)urowf[i1] + 1e-10) + 1e-10);
        best = (double)q1 / (g1 + 1e-10);
        bidx = i1;
        double g2 = -log(-log((double)urowf[i2] + 1e-10) + 1e-10);
        double rd = (double)q2 / (g2 + 1e-10);
        if (rd > best || (rd == best && i2 < bidx)) { best = rd; bidx = i2; }
    }

    for (int off = 32; off > 0; off >>= 1) {
        double ov = __shfl_down(best, off, 64);
        int oi = __shfl_down(bidx, off, 64);
        if (ov > best || (ov == best && oi < bidx)) { best = ov; bidx = oi; }
    }
    if ((tid & 63) == 0) { sRedD[tid >> 6] = best; sRedI[tid >> 6] = bidx; }
    __syncthreads();
    if (tid == 0) {
        best = sRedD[0]; bidx = sRedI[0];
        for (int w = 1; w < 16; ++w) {
            double ov = sRedD[w]; int oi = sRedI[w];
            if (ov > best || (ov == best && oi < bidx)) { best = ov; bidx = oi; }
        }
        int xv = xin[row];
        out[row] = (float)((xv == MASKID) ? bidx : xv);
    }
}

extern "C" void kernel_launch(void* const* d_in, const int* in_sizes, int n_in,
                              void* d_out, int out_size, void* d_ws, size_t ws_size,
                              hipStream_t stream) {
    const int* x = (const int*)d_in[0];
    const float* logits = (const float*)d_in[1];
    const float* t = (const float*)d_in[2];
    const float* u = (const float*)d_in[3];
    float* out = (float*)d_out;
    const int rows = in_sizes[0];  // B*S = 2048
    hipLaunchKernelGGL(mdlm_kernel, dim3(rows), dim3(NTHR), 0, stream,
                       x, logits, t, u, out, rows);
}

// Round 8
// 268.413 us; speedup vs baseline: 1.4509x; 1.4038x over previous
//
#include <hip/hip_runtime.h>

#define NVOC 32000
#define NV4  (NVOC / 4)   // 8000
#define MASKID 31999
#define NBINS 1024
#define NTHR 512
#define NWAVES (NTHR / 64)
#define LISTCAP 2048

typedef unsigned int u32;
typedef unsigned long long u64;

// log2-spaced bins from the f32 bit pattern of e in (0,1]: 64 bins/octave.
__device__ __forceinline__ int bin_e(float e) {
    int v = (int)(__float_as_uint(e) >> 17) - 6976;   // 6976 = (127-18)<<6
    v = v < 0 ? 0 : v;
    return v > (NBINS - 1) ? (NBINS - 1) : v;
}

// e in [0,1] -> fixed-point mass at 2^-32 (f32 arithmetic, monotone in e)
__device__ __forceinline__ u32 fix32(float e) {
    float x = e * 4294967296.0f;
    x = fminf(x, 4294967040.0f);
    return (u32)x;
}

__global__ __launch_bounds__(NTHR, 8) void mdlm_kernel(
    const int* __restrict__ xin,
    const float* __restrict__ logits,
    const float* __restrict__ tin,
    const float* __restrict__ uin,
    float* __restrict__ out,
    int rows)
{
    __shared__ u64 sHist[NBINS];        // 8 KB
    __shared__ u32 sList[LISTCAP];      // 8 KB
    __shared__ float sRedF[NWAVES];
    __shared__ int sRedI[NWAVES];
    __shared__ double sRedD[NWAVES];
    __shared__ float sZmax, sTT;
    __shared__ int sCnt, sB, sCross, sMaxDrop;
    __shared__ u32 sTau;
    __shared__ u64 sAs, sSfp;

    const int row = blockIdx.x;
    if (row >= rows) return;
    const int tid = threadIdx.x;
    const float4* lrow4 = (const float4*)(logits + (size_t)row * NVOC);
    const float4* urow4 = (const float4*)(uin + (size_t)row * NVOC);
    float* prow = out + (size_t)rows + (size_t)row * NVOC;

    sHist[tid] = 0ULL;
    sHist[tid + NTHR] = 0ULL;
    if (tid == 0) {
        sCnt = 0; sB = -1; sCross = 0; sMaxDrop = -1; sTau = 0xFFFFFFFFu;
        sAs = 0ULL; sSfp = 0ULL;
        sTT = tin[0];
    }
    __syncthreads();

    // ---- pass A: row max (global read #1) ----
    float lmax = -3.0e38f;
    for (int v4 = tid; v4 < NV4; v4 += NTHR) {
        float4 f = lrow4[v4];
        if (v4 == (MASKID >> 2)) f.w = -1000000.0f;   // MASKID % 4 == 3
        lmax = fmaxf(lmax, fmaxf(fmaxf(f.x, f.y), fmaxf(f.z, f.w)));
    }
    for (int off = 32; off > 0; off >>= 1)
        lmax = fmaxf(lmax, __shfl_down(lmax, off, 64));
    if ((tid & 63) == 0) sRedF[tid >> 6] = lmax;
    __syncthreads();
    if (tid == 0) {
        float m = sRedF[0];
        for (int w = 1; w < NWAVES; ++w) m = fmaxf(m, sRedF[w]);
        sZmax = m;
    }
    __syncthreads();
    const float zmax = sZmax;

    // ---- pass B: mass histogram (global read #2) ----
    for (int v4 = tid; v4 < NV4; v4 += NTHR) {
        float4 f = lrow4[v4];
        if (v4 == (MASKID >> 2)) f.w = -1000000.0f;
        float ex = __expf(f.x - zmax);
        float ey = __expf(f.y - zmax);
        float ez = __expf(f.z - zmax);
        float ew = __expf(f.w - zmax);
        atomicAdd(&sHist[bin_e(ex)], (u64)fix32(ex));
        atomicAdd(&sHist[bin_e(ey)], (u64)fix32(ey));
        atomicAdd(&sHist[bin_e(ez)], (u64)fix32(ez));
        atomicAdd(&sHist[bin_e(ew)], (u64)fix32(ew));
    }
    __syncthreads();

    // ---- pass C: inclusive suffix scan over bins; Z = sHist[0] afterwards ----
    for (int dlt = 1; dlt < NBINS; dlt <<= 1) {
        u64 v0 = (tid + dlt < NBINS) ? sHist[tid + dlt] : 0ULL;
        u64 v1 = (tid + NTHR + dlt < NBINS) ? sHist[tid + NTHR + dlt] : 0ULL;
        __syncthreads();
        sHist[tid] += v0;
        sHist[tid + NTHR] += v1;
        __syncthreads();
    }
    const double T = 0.9 * (double)sHist[0];
    // crossing detection: A_strict(k) < T < A_incl(k), two bins per thread
    {
#pragma unroll
        for (int h = 0; h < 2; ++h) {
            int b = tid + h * NTHR;
            u64 Ai = sHist[b];
            u64 As = (b + 1 < NBINS) ? sHist[b + 1] : 0ULL;
            bool dropped = ((double)As >= T);
            bool keptf = ((double)Ai <= T);
            if (dropped) atomicMax(&sMaxDrop, b);
            if (!dropped && !keptf) { sB = b; sCross = 1; }
        }
    }
    __syncthreads();
    if (tid == 0) {
        int B = sCross ? sB : sMaxDrop;
        sB = B;
        u64 As;
        if (B < 0) As = sHist[0];                       // nothing dropped: keep all
        else As = (B + 1 < NBINS) ? sHist[B + 1] : 0ULL;
        sAs = As;
        if (!sCross) sSfp = As;                         // kept mass = strict-above B
    }
    __syncthreads();

    const int Bst = sB;
    const int cross = sCross;

    // ---- pass D/E: exact resolution inside the crossing bin (global read #3) ----
    if (cross) {
        for (int v4 = tid; v4 < NV4; v4 += NTHR) {
            float4 f = lrow4[v4];
            if (v4 == (MASKID >> 2)) f.w = -1000000.0f;
            float ee[4];
            ee[0] = __expf(f.x - zmax);
            ee[1] = __expf(f.y - zmax);
            ee[2] = __expf(f.z - zmax);
            ee[3] = __expf(f.w - zmax);
#pragma unroll
            for (int e4 = 0; e4 < 4; ++e4) {
                if (bin_e(ee[e4]) == Bst) {
                    int pos = atomicAdd(&sCnt, 1);
                    if (pos < LISTCAP) sList[pos] = fix32(ee[e4]);
                }
            }
        }
        __syncthreads();
        const int K = sCnt < LISTCAP ? sCnt : LISTCAP;
        for (int jj = tid; jj < K; jj += NTHR) {
            u32 mj = sList[jj];
            u64 s = sAs;
            for (int q2 = 0; q2 < K; ++q2) {
                u32 mv = sList[q2];
                if (mv >= mj) s += (u64)mv;
            }
            if ((double)s <= T) atomicMin(&sTau, mj);   // kept
        }
        __syncthreads();
        if (tid == 0) sSfp = sAs;
        __syncthreads();
        u32 tl = sTau;
        if (tl != 0xFFFFFFFFu) {
            u64 part = 0ULL;
            for (int q2 = tid; q2 < K; q2 += NTHR) {
                u32 mv = sList[q2];
                if (mv >= tl) part += (u64)mv;
            }
            if (part) atomicAdd(&sSfp, part);
        }
        __syncthreads();
    }

    // unified kept threshold: kept <=> fix32(e) >= tauU
    u32 tauU;
    {
        u32 tv = sTau;
        u32 edgefix = 0u;
        if (Bst >= 0) edgefix = fix32(__uint_as_float((u32)(Bst + 1 + 6976) << 17));
        if (cross) tauU = (tv != 0xFFFFFFFFu) ? tv : edgefix;
        else       tauU = (Bst < 0) ? 0u : edgefix;
    }

    const double invSd = 4294967296.0 / (double)sSfp;
    const float invSf = (float)invSd;

    // mask_prob in f64, replicating the reference expression order
    double mpd, omd;
    {
        double td = (double)sTT;
        mpd = ((1.0 - 1e-3) * (td - 0.05)) / ((1.0 - 1e-3) * td);
        omd = 1.0 - mpd;
    }
    const float mqf = (float)(mpd / omd);   // mask candidate in om-scaled units

    // ---- pass F: write p_x0, screen r' = p/g (om dropped: order-preserving),
    //              track top-2 (r', p, i) per thread (global read #4) ----
    float r1 = -3.0e38f, r2 = -3.0e38f;
    float q1 = 0.0f,     q2 = 0.0f;
    int   i1 = 0,        i2 = 0;
    for (int v4 = tid; v4 < NV4; v4 += NTHR) {
        float4 uf = urow4[v4];
        float4 f = lrow4[v4];
        if (v4 == (MASKID >> 2)) f.w = -1000000.0f;
        float ee[4], uu[4] = {uf.x, uf.y, uf.z, uf.w};
        ee[0] = __expf(f.x - zmax);
        ee[1] = __expf(f.y - zmax);
        ee[2] = __expf(f.z - zmax);
        ee[3] = __expf(f.w - zmax);
        float4 po;
        float pp[4];
        const int i0 = v4 * 4;
#pragma unroll
        for (int e4 = 0; e4 < 4; ++e4) {
            float e = ee[e4];
            float p = (fix32(e) >= tauU) ? e * invSf : 0.0f;
            pp[e4] = p;
            float g = -__logf(1e-10f - __logf(uu[e4] + 1e-10f));
            float r = p * __builtin_amdgcn_rcpf(g + 1e-10f);
            if (r > r1)      { r2 = r1; q2 = q1; i2 = i1; r1 = r; q1 = p; i1 = i0 + e4; }
            else if (r > r2) { r2 = r;  q2 = p;  i2 = i0 + e4; }
        }
        po.x = pp[0]; po.y = pp[1]; po.z = pp[2]; po.w = pp[3];
        ((float4*)prow)[v4] = po;
    }
    // inject the MASK candidate (om-scaled q = mp/om)
    if (tid == ((MASKID >> 2) % NTHR)) {
        float um = ((const float*)urow4)[MASKID];
        float g = -__logf(1e-10f - __logf(um + 1e-10f));
        float rm = mqf * __builtin_amdgcn_rcpf(g + 1e-10f);
        if (rm > r1)      { r2 = r1; q2 = q1; i2 = i1; r1 = rm; q1 = 0.0f; i1 = MASKID; }
        else if (rm > r2) { r2 = rm; q2 = 0.0f; i2 = MASKID; }
    }

    // ---- refine the 2 candidates: exact f64 ratio (g is the critical part) ----
    double best; int bidx;
    {
        const float* urowf = (const float*)urow4;
        double qa = (i1 == MASKID) ? mpd : (double)q1 * omd;
        double g1 = -log(-log((double)urowf[i1] + 1e-10) + 1e-10);
        best = qa / (g1 + 1e-10);
        bidx = i1;
        double qb = (i2 == MASKID) ? mpd : (double)q2 * omd;
        double g2 = -log(-log((double)urowf[i2] + 1e-10) + 1e-10);
        double rd = qb / (g2 + 1e-10);
        if (rd > best || (rd == best && i2 < bidx)) { best = rd; bidx = i2; }
    }

    for (int off = 32; off > 0; off >>= 1) {
        double ov = __shfl_down(best, off, 64);
        int oi = __shfl_down(bidx, off, 64);
        if (ov > best || (ov == best && oi < bidx)) { best = ov; bidx = oi; }
    }
    if ((tid & 63) == 0) { sRedD[tid >> 6] = best; sRedI[tid >> 6] = bidx; }
    __syncthreads();
    if (tid == 0) {
        best = sRedD[0]; bidx = sRedI[0];
        for (int w = 1; w < NWAVES; ++w) {
            double ov = sRedD[w]; int oi = sRedI[w];
            if (ov > best || (ov == best && oi < bidx)) { best = ov; bidx = oi; }
        }
        int xv = xin[row];
        out[row] = (float)((xv == MASKID) ? bidx : xv);
    }
}

extern "C" void kernel_launch(void* const* d_in, const int* in_sizes, int n_in,
                              void* d_out, int out_size, void* d_ws, size_t ws_size,
                              hipStream_t stream) {
    const int* x = (const int*)d_in[0];
    const float* logits = (const float*)d_in[1];
    const float* t = (const float*)d_in[2];
    const float* u = (const float*)d_in[3];
    float* out = (float*)d_out;
    const int rows = in_sizes[0];  // B*S = 2048
    hipLaunchKernelGGL(mdlm_kernel, dim3(rows), dim3(NTHR), 0, stream,
                       x, logits, t, u, out, rows);
}